// Round 3
// baseline (436.411 us; speedup 1.0000x reference)
//
#include <hip/hip_runtime.h>
#include <math.h>

#define WAVE 64
#define FXSCALE 4398046511104.0   // 2^42

// h[i] = dot(x[i,:], W) in fp64   (one 32-lane half-wave per row, float4 loads)
__global__ void k_h(const float* __restrict__ x, const float* __restrict__ W,
                    double* __restrict__ h, int N, int C) {
    int t = blockIdx.x * blockDim.x + threadIdx.x;
    int row = t >> 5;
    int lane = t & 31;
    if (row >= N) return;
    const float4* xr = (const float4*)(x + (size_t)row * C);
    const float4* w4 = (const float4*)W;
    int C4 = C >> 2;
    double acc = 0.0;
    for (int c = lane; c < C4; c += 32) {
        float4 xv = xr[c];
        float4 wv = w4[c];
        acc += (double)xv.x * (double)wv.x + (double)xv.y * (double)wv.y
             + (double)xv.z * (double)wv.z + (double)xv.w * (double)wv.w;
    }
    #pragma unroll
    for (int o = 16; o > 0; o >>= 1) acc += __shfl_xor(acc, o);
    if (lane == 0) h[row] = acc;
}

__global__ void k_deg(const int* __restrict__ col, int* __restrict__ degI, int E) {
    int e = blockIdx.x * blockDim.x + threadIdx.x;
    if (e < E) atomicAdd(&degI[col[e]], 1);
}

__global__ void k_dis(const int* __restrict__ degI, double* __restrict__ dis, int N) {
    int i = blockIdx.x * blockDim.x + threadIdx.x;
    if (i < N) dis[i] = 1.0 / sqrt((double)degI[i] + 1.0);
}

// fixed-point deterministic aggregation: aggI[col] += round((h[row]*dis[row]*dis[col]) * 2^42)
__global__ void k_agg(const int* __restrict__ row, const int* __restrict__ col,
                      const double* __restrict__ h, const double* __restrict__ dis,
                      unsigned long long* __restrict__ aggI, int E) {
    int e = blockIdx.x * blockDim.x + threadIdx.x;
    if (e >= E) return;
    int r = row[e], c = col[e];
    double term = h[r] * dis[r] * dis[c];
    long long q = __double2ll_rn(term * FXSCALE);
    atomicAdd(&aggI[c], (unsigned long long)q);
}

// score (fp64 exact, rounded to fp32) ; tg = tanh(score) fp32
__global__ void k_score(const unsigned long long* __restrict__ aggI,
                        const double* __restrict__ h, const double* __restrict__ dis,
                        const float* __restrict__ bptr,
                        float* __restrict__ score32, float* __restrict__ tg, int N) {
    int i = blockIdx.x * blockDim.x + threadIdx.x;
    if (i >= N) return;
    double agg = (double)(long long)aggI[i] / FXSCALE;
    double d = dis[i];
    double sc = (agg + h[i] * (d * d)) + (double)bptr[0];
    float s32 = (float)sc;
    score32[i] = s32;
    tg[i] = (float)tanh(sc);
}

// One THREAD per segment. Pure fp32, index order, FMA-free — mimics a numpy
// fp32 mirror of the reference: materialize e (rounded), Z = sequential sum,
// p = e/Z (rounded, materialized), stats on rounded p, var = sq/cnt - mean^2,
// cutoff = pmax - alpha*std, keep = p >= cutoff.
__global__ void k_seg_np(const float* __restrict__ score32, const int* __restrict__ starts,
                         float* __restrict__ p32, int* __restrict__ keepI,
                         const int* __restrict__ alphaPtr, int N, int S) {
    int g = blockIdx.x * blockDim.x + threadIdx.x;
    if (g >= S) return;
    int st = starts[g];
    int en = (g == S - 1) ? N : starts[g + 1];
    if (en <= st) return;

    int ai = alphaPtr[0];
    float alpha = (ai >= 0 && ai < 1000000) ? (float)ai : __int_as_float(ai);

    float m = -3.402823466e38f;
    for (int i = st; i < en; i++) m = fmaxf(m, score32[i]);

    float Z = 0.0f;
    for (int i = st; i < en; i++) {
        float dm = __fsub_rn(score32[i], m);
        float e = (float)exp((double)dm);   // correctly-rounded fp32 exp
        p32[i] = e;
        Z = __fadd_rn(Z, e);
    }

    float sp = 0.0f, sq = 0.0f, pm = -3.402823466e38f;
    for (int i = st; i < en; i++) {
        float p = __fdiv_rn(p32[i], Z);
        p32[i] = p;
        sp = __fadd_rn(sp, p);
        sq = __fadd_rn(sq, __fmul_rn(p, p));
        pm = fmaxf(pm, p);
    }

    float cnt = (float)(en - st);
    float mean = __fdiv_rn(sp, cnt);
    float var = __fsub_rn(__fdiv_rn(sq, cnt), __fmul_rn(mean, mean));
    float sd = sqrtf(fmaxf(var, 0.0f));
    float cutoff = __fsub_rn(pm, __fmul_rn(alpha, sd));

    for (int i = st; i < en; i++) keepI[i] = (p32[i] >= cutoff) ? 1 : 0;
}

__global__ void k_union(const int* __restrict__ n1, const int* __restrict__ n2,
                        const int* __restrict__ sent, int* __restrict__ keepI, int S) {
    int i = blockIdx.x * blockDim.x + threadIdx.x;
    if (i >= S) return;
    keepI[n1[i]] = 1;
    keepI[n2[i]] = 1;
    keepI[sent[i]] = 1;
}

#define SCAN_CHUNK 2048  // 256 threads * 8

__global__ void k_scanA(const int* __restrict__ keepI, int* __restrict__ bs, int N) {
    int tid = threadIdx.x;
    long base = (long)blockIdx.x * SCAN_CHUNK + (long)tid * 8;
    int s = 0;
    #pragma unroll
    for (int k = 0; k < 8; k++) { long i = base + k; if (i < N) s += keepI[i]; }
    __shared__ int sm[256];
    sm[tid] = s; __syncthreads();
    for (int off = 128; off > 0; off >>= 1) {
        if (tid < off) sm[tid] += sm[tid + off];
        __syncthreads();
    }
    if (tid == 0) bs[blockIdx.x] = sm[0];
}

__global__ void k_scanB(const int* __restrict__ bs, int* __restrict__ bo, int nb) {
    __shared__ int sm[256];
    __shared__ int carrySh;
    int tid = threadIdx.x;
    if (tid == 0) carrySh = 0;
    __syncthreads();
    for (int base = 0; base < nb; base += 256) {
        int i = base + tid;
        int v = (i < nb) ? bs[i] : 0;
        sm[tid] = v; __syncthreads();
        for (int off = 1; off < 256; off <<= 1) {
            int t = (tid >= off) ? sm[tid - off] : 0;
            __syncthreads();
            sm[tid] += t;
            __syncthreads();
        }
        int incl = sm[tid];
        int total = sm[255];
        int carry = carrySh;
        if (i < nb) bo[i] = carry + incl - v;
        __syncthreads();
        if (tid == 0) carrySh = carry + total;
        __syncthreads();
    }
}

__global__ void k_scanC(const int* __restrict__ keepI, const int* __restrict__ bo,
                        int* __restrict__ pos, float* __restrict__ o_keep, int N) {
    int tid = threadIdx.x;
    long base = (long)blockIdx.x * SCAN_CHUNK + (long)tid * 8;
    int v[8];
    int th = 0;
    #pragma unroll
    for (int k = 0; k < 8; k++) {
        long i = base + k;
        v[k] = (i < N) ? keepI[i] : 0;
        th += v[k];
    }
    __shared__ int sm[256];
    sm[tid] = th; __syncthreads();
    for (int off = 1; off < 256; off <<= 1) {
        int t = (tid >= off) ? sm[tid - off] : 0;
        __syncthreads();
        sm[tid] += t;
        __syncthreads();
    }
    int excl = sm[tid] - th;
    int run = bo[blockIdx.x] + excl;
    #pragma unroll
    for (int k = 0; k < 8; k++) {
        long i = base + k;
        if (i < N) {
            pos[i] = run + v[k] - 1;
            o_keep[i] = v[k] ? 1.0f : 0.0f;
            run += v[k];
        }
    }
}

// x_out: one float4 per thread
__global__ void k_xout(const float4* __restrict__ x4, const int* __restrict__ keepI,
                       const float* __restrict__ tg, float4* __restrict__ o4,
                       long total) {
    long idx = blockIdx.x * (long)blockDim.x + threadIdx.x;
    if (idx >= total) return;
    int row = (int)(idx >> 5);   // C/4 = 32 float4 per row
    int kept = keepI[row];
    float g = kept ? tg[row] : 0.0f;
    float4 v = x4[idx];
    float4 r;
    r.x = v.x * g; r.y = v.y * g; r.z = v.z * g; r.w = v.w * g;
    o4[idx] = r;
}

__global__ void k_edges(const int* __restrict__ row, const int* __restrict__ col,
                        const int* __restrict__ keepI, const int* __restrict__ pos,
                        float* __restrict__ o_edge, float* __restrict__ o_ekeep, int E) {
    int e = blockIdx.x * blockDim.x + threadIdx.x;
    if (e >= E) return;
    int r = row[e], c = col[e];
    bool ek = keepI[r] && keepI[c];
    o_edge[e]             = ek ? (float)pos[r] : -1.0f;
    o_edge[(size_t)E + e] = ek ? (float)pos[c] : -1.0f;
    o_ekeep[e]            = ek ? 1.0f : 0.0f;
}

__global__ void k_nodes(const int* __restrict__ n1, const int* __restrict__ n2,
                        const int* __restrict__ sent, const int* __restrict__ pos,
                        float* __restrict__ o_n1, float* __restrict__ o_n2,
                        float* __restrict__ o_sent, int S) {
    int i = blockIdx.x * blockDim.x + threadIdx.x;
    if (i >= S) return;
    o_n1[i] = (float)pos[n1[i]];
    o_n2[i] = (float)pos[n2[i]];
    o_sent[i] = (float)pos[sent[i]];
}

extern "C" void kernel_launch(void* const* d_in, const int* in_sizes, int n_in,
                              void* d_out, int out_size, void* d_ws, size_t ws_size,
                              hipStream_t stream) {
    const float* x    = (const float*)d_in[0];
    const int*   eidx = (const int*)d_in[1];
    const int*   n1   = (const int*)d_in[2];
    const int*   n2   = (const int*)d_in[3];
    const int*   sent = (const int*)d_in[4];
    const float* W    = (const float*)d_in[5];
    const float* bp   = (const float*)d_in[6];
    const int*   alphaPtr = (const int*)d_in[7];

    int C = in_sizes[5];                 // W is [C,1]
    int N = in_sizes[0] / C;
    int E = in_sizes[1] / 2;
    int S = in_sizes[2];

    const int* erow = eidx;
    const int* ecol = eidx + E;

    // workspace layout
    char* ws = (char*)d_ws;
    size_t off = 0;
    auto alloc = [&](size_t bytes) { void* p = ws + off; off += (bytes + 255) & ~(size_t)255; return p; };
    double* h     = (double*)alloc((size_t)N * 8);
    double* dis   = (double*)alloc((size_t)N * 8);
    unsigned long long* aggI = (unsigned long long*)alloc((size_t)N * 8);
    float* score32 = (float*)alloc((size_t)N * 4);
    float* p32    = (float*)alloc((size_t)N * 4);
    int*   degI  = (int*)  alloc((size_t)N * 4);
    float* tg    = (float*)alloc((size_t)N * 4);
    int*   keepI = (int*)  alloc((size_t)N * 4);
    int*   pos   = (int*)  alloc((size_t)N * 4);
    int nb = (N + SCAN_CHUNK - 1) / SCAN_CHUNK;
    int*   bs    = (int*)  alloc((size_t)nb * 4);
    int*   bo    = (int*)  alloc((size_t)nb * 4);

    // output layout (all float32, concatenated)
    float* o_x     = (float*)d_out;
    float* o_edge  = o_x + (size_t)N * C;
    float* o_keep  = o_edge + 2 * (size_t)E;
    float* o_ekeep = o_keep + N;
    float* o_n1    = o_ekeep + E;
    float* o_n2    = o_n1 + S;
    float* o_sent  = o_n2 + S;

    hipMemsetAsync(degI, 0, (size_t)N * 4, stream);
    hipMemsetAsync(aggI, 0, (size_t)N * 8, stream);

    k_h<<<(N * 32 + 255) / 256, 256, 0, stream>>>(x, W, h, N, C);
    k_deg<<<(E + 255) / 256, 256, 0, stream>>>(ecol, degI, E);
    k_dis<<<(N + 255) / 256, 256, 0, stream>>>(degI, dis, N);
    k_agg<<<(E + 255) / 256, 256, 0, stream>>>(erow, ecol, h, dis, aggI, E);
    k_score<<<(N + 255) / 256, 256, 0, stream>>>(aggI, h, dis, bp, score32, tg, N);
    k_seg_np<<<(S + 255) / 256, 256, 0, stream>>>(score32, n1, p32, keepI, alphaPtr, N, S);
    k_union<<<(S + 255) / 256, 256, 0, stream>>>(n1, n2, sent, keepI, S);
    k_scanA<<<nb, 256, 0, stream>>>(keepI, bs, N);
    k_scanB<<<1, 256, 0, stream>>>(bs, bo, nb);
    k_scanC<<<nb, 256, 0, stream>>>(keepI, bo, pos, o_keep, N);
    long total4 = (long)N * (C / 4);
    k_xout<<<(int)((total4 + 255) / 256), 256, 0, stream>>>((const float4*)x, keepI, tg, (float4*)o_x, total4);
    k_edges<<<(E + 255) / 256, 256, 0, stream>>>(erow, ecol, keepI, pos, o_edge, o_ekeep, E);
    k_nodes<<<(S + 255) / 256, 256, 0, stream>>>(n1, n2, sent, pos, o_n1, o_n2, o_sent, S);
}

// Round 5
// 434.929 us; speedup vs baseline: 1.0034x; 1.0034x over previous
//
#include <hip/hip_runtime.h>
#include <math.h>

#define WAVE 64
#define FXSCALE 4398046511104.0   // 2^42

typedef float vfloat4 __attribute__((ext_vector_type(4)));

// h[i] = dot(x[i,:], W) in fp64   (one 32-lane half-wave per row, float4 loads)
__global__ void k_h(const float* __restrict__ x, const float* __restrict__ W,
                    double* __restrict__ h, int N, int C) {
    int t = blockIdx.x * blockDim.x + threadIdx.x;
    int row = t >> 5;
    int lane = t & 31;
    if (row >= N) return;
    const float4* xr = (const float4*)(x + (size_t)row * C);
    const float4* w4 = (const float4*)W;
    int C4 = C >> 2;
    double acc = 0.0;
    for (int c = lane; c < C4; c += 32) {
        float4 xv = xr[c];
        float4 wv = w4[c];
        acc += (double)xv.x * (double)wv.x + (double)xv.y * (double)wv.y
             + (double)xv.z * (double)wv.z + (double)xv.w * (double)wv.w;
    }
    #pragma unroll
    for (int o = 16; o > 0; o >>= 1) acc += __shfl_xor(acc, o);
    if (lane == 0) h[row] = acc;
}

// sharded degree histogram: degsh[(e & mask)*N + col[e]] += 1
__global__ void k_deg(const int* __restrict__ col, int* __restrict__ degsh,
                      int E, int N, int shMask) {
    int e = blockIdx.x * blockDim.x + threadIdx.x;
    if (e >= E) return;
    int k = e & shMask;
    atomicAdd(&degsh[(size_t)k * N + col[e]], 1);
}

__global__ void k_dis(const int* __restrict__ degsh, double* __restrict__ dis,
                      int N, int nsh) {
    int i = blockIdx.x * blockDim.x + threadIdx.x;
    if (i >= N) return;
    int d = 0;
    for (int k = 0; k < nsh; k++) d += degsh[(size_t)k * N + i];
    dis[i] = 1.0 / sqrt((double)d + 1.0);
}

// sharded fixed-point aggregation (order-free => deterministic, exact vs unsharded)
__global__ void k_agg(const int* __restrict__ row, const int* __restrict__ col,
                      const double* __restrict__ h, const double* __restrict__ dis,
                      unsigned long long* __restrict__ aggsh, int E, int N, int shMask) {
    int e = blockIdx.x * blockDim.x + threadIdx.x;
    if (e >= E) return;
    int r = row[e], c = col[e];
    double term = h[r] * dis[r] * dis[c];
    long long q = __double2ll_rn(term * FXSCALE);
    int k = e & shMask;
    atomicAdd(&aggsh[(size_t)k * N + c], (unsigned long long)q);
}

// score (fp64 exact, rounded to fp32) ; tg = tanh(score) fp32
__global__ void k_score(const unsigned long long* __restrict__ aggsh,
                        const double* __restrict__ h, const double* __restrict__ dis,
                        const float* __restrict__ bptr,
                        float* __restrict__ score32, float* __restrict__ tg,
                        int N, int nsh) {
    int i = blockIdx.x * blockDim.x + threadIdx.x;
    if (i >= N) return;
    long long acc = 0;
    for (int k = 0; k < nsh; k++) acc += (long long)aggsh[(size_t)k * N + i];
    double agg = (double)acc / FXSCALE;
    double d = dis[i];
    double sc = (agg + h[i] * (d * d)) + (double)bptr[0];
    score32[i] = (float)sc;
    tg[i] = (float)tanh(sc);
}

// One THREAD per segment — numerics byte-identical to the passing round-3 kernel.
__global__ void k_seg_np(const float* __restrict__ score32, const int* __restrict__ starts,
                         float* __restrict__ p32, int* __restrict__ keepI,
                         const int* __restrict__ alphaPtr, int N, int S) {
    int g = blockIdx.x * blockDim.x + threadIdx.x;
    if (g >= S) return;
    int st = starts[g];
    int en = (g == S - 1) ? N : starts[g + 1];
    if (en <= st) return;

    int ai = alphaPtr[0];
    float alpha = (ai >= 0 && ai < 1000000) ? (float)ai : __int_as_float(ai);

    float m = -3.402823466e38f;
    for (int i = st; i < en; i++) m = fmaxf(m, score32[i]);

    float Z = 0.0f;
    for (int i = st; i < en; i++) {
        float dm = __fsub_rn(score32[i], m);
        float e = (float)exp((double)dm);   // correctly-rounded fp32 exp
        p32[i] = e;
        Z = __fadd_rn(Z, e);
    }

    float sp = 0.0f, sq = 0.0f, pm = -3.402823466e38f;
    for (int i = st; i < en; i++) {
        float p = __fdiv_rn(p32[i], Z);
        p32[i] = p;
        sp = __fadd_rn(sp, p);
        sq = __fadd_rn(sq, __fmul_rn(p, p));
        pm = fmaxf(pm, p);
    }

    float cnt = (float)(en - st);
    float mean = __fdiv_rn(sp, cnt);
    float var = __fsub_rn(__fdiv_rn(sq, cnt), __fmul_rn(mean, mean));
    float sd = sqrtf(fmaxf(var, 0.0f));
    float cutoff = __fsub_rn(pm, __fmul_rn(alpha, sd));

    for (int i = st; i < en; i++) keepI[i] = (p32[i] >= cutoff) ? 1 : 0;
}

__global__ void k_union(const int* __restrict__ n1, const int* __restrict__ n2,
                        const int* __restrict__ sent, int* __restrict__ keepI, int S) {
    int i = blockIdx.x * blockDim.x + threadIdx.x;
    if (i >= S) return;
    keepI[n1[i]] = 1;
    keepI[n2[i]] = 1;
    keepI[sent[i]] = 1;
}

#define SCAN_CHUNK 2048  // 256 threads * 8

__global__ void k_scanA(const int* __restrict__ keepI, int* __restrict__ bs, int N) {
    int tid = threadIdx.x;
    long base = (long)blockIdx.x * SCAN_CHUNK + (long)tid * 8;
    int s = 0;
    #pragma unroll
    for (int k = 0; k < 8; k++) { long i = base + k; if (i < N) s += keepI[i]; }
    __shared__ int sm[256];
    sm[tid] = s; __syncthreads();
    for (int off = 128; off > 0; off >>= 1) {
        if (tid < off) sm[tid] += sm[tid + off];
        __syncthreads();
    }
    if (tid == 0) bs[blockIdx.x] = sm[0];
}

__global__ void k_scanB(const int* __restrict__ bs, int* __restrict__ bo, int nb) {
    __shared__ int sm[256];
    __shared__ int carrySh;
    int tid = threadIdx.x;
    if (tid == 0) carrySh = 0;
    __syncthreads();
    for (int base = 0; base < nb; base += 256) {
        int i = base + tid;
        int v = (i < nb) ? bs[i] : 0;
        sm[tid] = v; __syncthreads();
        for (int off = 1; off < 256; off <<= 1) {
            int t = (tid >= off) ? sm[tid - off] : 0;
            __syncthreads();
            sm[tid] += t;
            __syncthreads();
        }
        int incl = sm[tid];
        int total = sm[255];
        int carry = carrySh;
        if (i < nb) bo[i] = carry + incl - v;
        __syncthreads();
        if (tid == 0) carrySh = carry + total;
        __syncthreads();
    }
}

__global__ void k_scanC(const int* __restrict__ keepI, const int* __restrict__ bo,
                        int* __restrict__ pos, float* __restrict__ o_keep, int N) {
    int tid = threadIdx.x;
    long base = (long)blockIdx.x * SCAN_CHUNK + (long)tid * 8;
    int v[8];
    int th = 0;
    #pragma unroll
    for (int k = 0; k < 8; k++) {
        long i = base + k;
        v[k] = (i < N) ? keepI[i] : 0;
        th += v[k];
    }
    __shared__ int sm[256];
    sm[tid] = th; __syncthreads();
    for (int off = 1; off < 256; off <<= 1) {
        int t = (tid >= off) ? sm[tid - off] : 0;
        __syncthreads();
        sm[tid] += t;
        __syncthreads();
    }
    int excl = sm[tid] - th;
    int run = bo[blockIdx.x] + excl;
    #pragma unroll
    for (int k = 0; k < 8; k++) {
        long i = base + k;
        if (i < N) {
            pos[i] = run + v[k] - 1;
            o_keep[i] = v[k] ? 1.0f : 0.0f;
            run += v[k];
        }
    }
}

// fused outputs: [0, nxb) -> x_out float4s; [nxb, nxb+neb) -> edges; rest -> nodes
__global__ void k_out(const float4* __restrict__ x4, const int* __restrict__ keepI,
                      const float* __restrict__ tg, float* __restrict__ o_x, long total4,
                      const int* __restrict__ erow, const int* __restrict__ ecol,
                      const int* __restrict__ pos,
                      float* __restrict__ o_edge, float* __restrict__ o_ekeep, int E,
                      const int* __restrict__ n1, const int* __restrict__ n2,
                      const int* __restrict__ sent,
                      float* __restrict__ o_n1, float* __restrict__ o_n2,
                      float* __restrict__ o_sent, int S,
                      int nxb, int neb) {
    int b = blockIdx.x;
    if (b < nxb) {
        long idx = (long)b * blockDim.x + threadIdx.x;
        if (idx >= total4) return;
        int row = (int)(idx >> 5);   // C/4 = 32 float4 per row
        int kept = keepI[row];
        float g = kept ? tg[row] : 0.0f;
        float4 v = x4[idx];
        vfloat4 r = { v.x * g, v.y * g, v.z * g, v.w * g };
        __builtin_nontemporal_store(r, (vfloat4*)o_x + idx);
    } else if (b < nxb + neb) {
        int e = (b - nxb) * blockDim.x + threadIdx.x;
        if (e >= E) return;
        int r = erow[e], c = ecol[e];
        bool ek = keepI[r] && keepI[c];
        __builtin_nontemporal_store(ek ? (float)pos[r] : -1.0f, &o_edge[e]);
        __builtin_nontemporal_store(ek ? (float)pos[c] : -1.0f, &o_edge[(size_t)E + e]);
        __builtin_nontemporal_store(ek ? 1.0f : 0.0f, &o_ekeep[e]);
    } else {
        int i = (b - nxb - neb) * blockDim.x + threadIdx.x;
        if (i >= S) return;
        o_n1[i] = (float)pos[n1[i]];
        o_n2[i] = (float)pos[n2[i]];
        o_sent[i] = (float)pos[sent[i]];
    }
}

extern "C" void kernel_launch(void* const* d_in, const int* in_sizes, int n_in,
                              void* d_out, int out_size, void* d_ws, size_t ws_size,
                              hipStream_t stream) {
    const float* x    = (const float*)d_in[0];
    const int*   eidx = (const int*)d_in[1];
    const int*   n1   = (const int*)d_in[2];
    const int*   n2   = (const int*)d_in[3];
    const int*   sent = (const int*)d_in[4];
    const float* W    = (const float*)d_in[5];
    const float* bp   = (const float*)d_in[6];
    const int*   alphaPtr = (const int*)d_in[7];

    int C = in_sizes[5];                 // W is [C,1]
    int N = in_sizes[0] / C;
    int E = in_sizes[1] / 2;
    int S = in_sizes[2];

    const int* erow = eidx;
    const int* ecol = eidx + E;

    // pick shard count that fits ws (deterministic given fixed ws_size)
    size_t fixedBytes = (size_t)N * (8 + 8 + 4 + 4 + 4 + 4 + 4) + (1 << 20);
    int nsh = 16;
    while (nsh > 1 && fixedBytes + (size_t)nsh * N * 12 + 4096 > ws_size) nsh >>= 1;
    int shMask = nsh - 1;

    // workspace layout (aggsh+degsh contiguous for a single memset)
    char* ws = (char*)d_ws;
    size_t off = 0;
    auto alloc = [&](size_t bytes) { void* p = ws + off; off += (bytes + 255) & ~(size_t)255; return p; };
    unsigned long long* aggsh = (unsigned long long*)alloc((size_t)nsh * N * 8);
    int*   degsh = (int*)  alloc((size_t)nsh * N * 4);
    size_t zeroBytes = (size_t)((char*)(degsh + (size_t)nsh * N) - (char*)aggsh);
    double* h     = (double*)alloc((size_t)N * 8);
    double* dis   = (double*)alloc((size_t)N * 8);
    float* score32 = (float*)alloc((size_t)N * 4);
    float* p32    = (float*)alloc((size_t)N * 4);
    float* tg    = (float*)alloc((size_t)N * 4);
    int*   keepI = (int*)  alloc((size_t)N * 4);
    int*   pos   = (int*)  alloc((size_t)N * 4);
    int nb = (N + SCAN_CHUNK - 1) / SCAN_CHUNK;
    int*   bs    = (int*)  alloc((size_t)nb * 4);
    int*   bo    = (int*)  alloc((size_t)nb * 4);

    // output layout (all float32, concatenated)
    float* o_x     = (float*)d_out;
    float* o_edge  = o_x + (size_t)N * C;
    float* o_keep  = o_edge + 2 * (size_t)E;
    float* o_ekeep = o_keep + N;
    float* o_n1    = o_ekeep + E;
    float* o_n2    = o_n1 + S;
    float* o_sent  = o_n2 + S;

    (void)hipMemsetAsync(aggsh, 0, zeroBytes, stream);

    k_h<<<(N * 32 + 255) / 256, 256, 0, stream>>>(x, W, h, N, C);
    k_deg<<<(E + 255) / 256, 256, 0, stream>>>(ecol, degsh, E, N, shMask);
    k_dis<<<(N + 255) / 256, 256, 0, stream>>>(degsh, dis, N, nsh);
    k_agg<<<(E + 255) / 256, 256, 0, stream>>>(erow, ecol, h, dis, aggsh, E, N, shMask);
    k_score<<<(N + 255) / 256, 256, 0, stream>>>(aggsh, h, dis, bp, score32, tg, N, nsh);
    k_seg_np<<<(S + 255) / 256, 256, 0, stream>>>(score32, n1, p32, keepI, alphaPtr, N, S);
    k_union<<<(S + 255) / 256, 256, 0, stream>>>(n1, n2, sent, keepI, S);
    k_scanA<<<nb, 256, 0, stream>>>(keepI, bs, N);
    k_scanB<<<1, 256, 0, stream>>>(bs, bo, nb);
    k_scanC<<<nb, 256, 0, stream>>>(keepI, bo, pos, o_keep, N);

    long total4 = (long)N * (C / 4);
    int nxb = (int)((total4 + 255) / 256);
    int neb = (E + 255) / 256;
    int nsb = (S + 255) / 256;
    k_out<<<nxb + neb + nsb, 256, 0, stream>>>(
        (const float4*)x, keepI, tg, o_x, total4,
        erow, ecol, pos, o_edge, o_ekeep, E,
        n1, n2, sent, o_n1, o_n2, o_sent, S, nxb, neb);
}